// Round 6
// baseline (205.185 us; speedup 1.0000x reference)
//
#include <hip/hip_runtime.h>
#include <hip/hip_bf16.h>
#include <cstdint>

#define L_SEQ 1024
#define HID_DIM 512
#define N_HEADS 8
#define HEAD_DIM 64
#define BATCH 8

typedef __attribute__((ext_vector_type(8))) short bf16x8;
typedef __attribute__((ext_vector_type(4))) float f32x4;

__device__ __forceinline__ ushort f2bf(float v) {
  __hip_bfloat16 hb = __float2bfloat16(v);
  return *(ushort*)&hb;
}

// Convert f32 -> bf16: x (4,194,304) then Wq,Wk,Wv,Wo (262,144 each).
__global__ __launch_bounds__(256)
void prep_convert(const float* __restrict__ x, const float* __restrict__ Wq,
                  const float* __restrict__ Wk, const float* __restrict__ Wv,
                  const float* __restrict__ Wo, ushort* __restrict__ dst) {
  const size_t gid = (size_t)blockIdx.x * 256 + threadIdx.x;
  const size_t e = gid * 8;
  const float* src;
  size_t loc;
  if (e < 4194304) {
    src = x; loc = e;
  } else {
    const size_t r = e - 4194304;
    const int wsel = (int)(r >> 18);
    loc = r & 262143;
    src = (wsel == 0) ? Wq : (wsel == 1) ? Wk : (wsel == 2) ? Wv : Wo;
  }
  float4 v0 = *(const float4*)(src + loc);
  float4 v1 = *(const float4*)(src + loc + 4);
  ushort u[8];
  u[0] = f2bf(v0.x); u[1] = f2bf(v0.y); u[2] = f2bf(v0.z); u[3] = f2bf(v0.w);
  u[4] = f2bf(v1.x); u[5] = f2bf(v1.y); u[6] = f2bf(v1.z); u[7] = f2bf(v1.w);
  *(uint4*)(dst + e) = *(uint4*)u;
}

// lens[b] = number of un-padded rows in batch b (layout-detecting; see round 3)
__global__ __launch_bounds__(256)
void lens_kernel(const uint8_t* __restrict__ pm, int* __restrict__ lens) {
  __shared__ int flag;
  __shared__ int part[256];
  const int b = blockIdx.x, tid = threadIdx.x;
  if (tid == 0) flag = 0;
  __syncthreads();
  const unsigned* pw = (const unsigned*)pm;
  unsigned any = 0;
  for (int i = tid; i < 2048; i += 256) any |= (pw[i] > 1u);
  if (any) flag = 1;
  __syncthreads();
  int c = 0;
  if (flag) {
    unsigned v = pw[b * 256 + tid];
    c = (int)((v & 0xFFu) == 0) + (int)(((v >> 8) & 0xFFu) == 0) +
        (int)(((v >> 16) & 0xFFu) == 0) + (int)(((v >> 24) & 0xFFu) == 0);
  } else {
    const int* pi = (const int*)pm;
    c = (int)(pi[b * 1024 + tid * 4 + 0] == 0) + (int)(pi[b * 1024 + tid * 4 + 1] == 0) +
        (int)(pi[b * 1024 + tid * 4 + 2] == 0) + (int)(pi[b * 1024 + tid * 4 + 3] == 0);
  }
  part[tid] = c;
  __syncthreads();
  for (int s = 128; s > 0; s >>= 1) {
    if (tid < s) part[tid] += part[tid + s];
    __syncthreads();
  }
  if (tid == 0) lens[b] = part[0];
}

#define LOAD_FRAGS4(av, bv, ks)                                             \
  {                                                                         \
    _Pragma("unroll") for (int t = 0; t < 4; ++t) {                         \
      av[t] = *(const bf16x8*)(Abase + (size_t)t * 16 * 512 + (ks) * 32);   \
      bv[t] = *(const bf16x8*)(Bbase + (size_t)t * 16 * 512 + (ks) * 32);   \
    }                                                                       \
  }
#define DO_MFMA44(av, bv)                                                   \
  {                                                                         \
    _Pragma("unroll") for (int i = 0; i < 4; ++i)                           \
        _Pragma("unroll") for (int j = 0; j < 4; ++j) acc[i][j] =           \
            __builtin_amdgcn_mfma_f32_16x16x32_bf16(av[i], bv[j],           \
                                                    acc[i][j], 0, 0, 0);    \
  }

// Fused QKV GEMM, 64x64 tile per 1-wave block. grid (128, 8, 3).
// z=0: Q = xb*Wq^T, z=1: K = xb*Wk^T  (bf16 row-major out)
// z=2: V^T = Wv*xb^T  (M=hid via blockIdx.y, N=token via blockIdx.x)
__global__ __launch_bounds__(64)
void qkv_gemm(const ushort* __restrict__ xb, const ushort* __restrict__ wqb,
              const ushort* __restrict__ wkb, const ushort* __restrict__ wvb,
              const float* __restrict__ bq, const float* __restrict__ bk,
              const float* __restrict__ bv, ushort* __restrict__ qb,
              ushort* __restrict__ kb, ushort* __restrict__ vT) {
  const int z = blockIdx.z;
  const int lane = threadIdx.x;
  const int l15 = lane & 15, g = lane >> 4;
  const ushort* A = (z == 2) ? wvb : xb;
  const ushort* B = (z == 0) ? wqb : (z == 1) ? wkb : xb;
  const float* bias = (z == 0) ? bq : (z == 1) ? bk : bv;
  const int M0 = ((z == 2) ? blockIdx.y : blockIdx.x) * 64;
  const int N0 = ((z == 2) ? blockIdx.x : blockIdx.y) * 64;

  const ushort* Abase = A + (size_t)(M0 + l15) * 512 + 8 * g;
  const ushort* Bbase = B + (size_t)(N0 + l15) * 512 + 8 * g;

  f32x4 acc[4][4];
#pragma unroll
  for (int i = 0; i < 4; ++i)
#pragma unroll
    for (int j = 0; j < 4; ++j) acc[i][j] = (f32x4){0.f, 0.f, 0.f, 0.f};

  bf16x8 aA[4], bA[4], aB[4], bB[4];
  LOAD_FRAGS4(aA, bA, 0);
  LOAD_FRAGS4(aB, bB, 1);
#pragma unroll
  for (int ks = 0; ks < 16; ks += 2) {
    DO_MFMA44(aA, bA);
    if (ks + 2 < 16) LOAD_FRAGS4(aA, bA, ks + 2);
    DO_MFMA44(aB, bB);
    if (ks + 3 < 16) LOAD_FRAGS4(aB, bB, ks + 3);
  }

  if (z < 2) {
    ushort* out = (z == 0) ? qb : kb;
    float bn[4];
#pragma unroll
    for (int nt = 0; nt < 4; ++nt) bn[nt] = bias[N0 + nt * 16 + l15];
#pragma unroll
    for (int mt = 0; mt < 4; ++mt)
#pragma unroll
      for (int nt = 0; nt < 4; ++nt)
#pragma unroll
        for (int r = 0; r < 4; ++r) {
          const int m = M0 + mt * 16 + 4 * g + r;
          const int n = N0 + nt * 16 + l15;
          out[(size_t)m * 512 + n] = f2bf(acc[mt][nt][r] + bn[nt]);
        }
  } else {
#pragma unroll
    for (int mt = 0; mt < 4; ++mt)
#pragma unroll
      for (int r = 0; r < 4; ++r) {
        const int m = M0 + mt * 16 + 4 * g + r;  // hid index of V
        const float bm = bias[m];
#pragma unroll
        for (int nt = 0; nt < 4; ++nt) {
          const int tok = N0 + nt * 16 + l15;
          const size_t off = ((size_t)((tok >> 10) * 512 + m)) * 1024 + (tok & 1023);
          vT[off] = f2bf(acc[mt][nt][r] + bm);
        }
      }
  }
}

// Final projection: out = ab*Wo^T + bo, f32 out. 32x64 tile. grid (256, 8).
__global__ __launch_bounds__(64)
void out_gemm(const ushort* __restrict__ A, const ushort* __restrict__ B,
              const float* __restrict__ bias, float* __restrict__ out) {
  const int lane = threadIdx.x;
  const int l15 = lane & 15, g = lane >> 4;
  const int M0 = blockIdx.x * 32, N0 = blockIdx.y * 64;
  const ushort* Abase = A + (size_t)(M0 + l15) * 512 + 8 * g;
  const ushort* Bbase = B + (size_t)(N0 + l15) * 512 + 8 * g;

  f32x4 acc[2][4];
#pragma unroll
  for (int i = 0; i < 2; ++i)
#pragma unroll
    for (int j = 0; j < 4; ++j) acc[i][j] = (f32x4){0.f, 0.f, 0.f, 0.f};

  bf16x8 aA[2], bA[4], aB[2], bB[4];
#define LOAD_FRAGS2(av, bv, ks)                                             \
  {                                                                         \
    _Pragma("unroll") for (int t = 0; t < 2; ++t)                           \
      av[t] = *(const bf16x8*)(Abase + (size_t)t * 16 * 512 + (ks) * 32);   \
    _Pragma("unroll") for (int t = 0; t < 4; ++t)                           \
      bv[t] = *(const bf16x8*)(Bbase + (size_t)t * 16 * 512 + (ks) * 32);   \
  }
#define DO_MFMA24(av, bv)                                                   \
  {                                                                         \
    _Pragma("unroll") for (int i = 0; i < 2; ++i)                           \
        _Pragma("unroll") for (int j = 0; j < 4; ++j) acc[i][j] =           \
            __builtin_amdgcn_mfma_f32_16x16x32_bf16(av[i], bv[j],           \
                                                    acc[i][j], 0, 0, 0);    \
  }
  LOAD_FRAGS2(aA, bA, 0);
  LOAD_FRAGS2(aB, bB, 1);
#pragma unroll
  for (int ks = 0; ks < 16; ks += 2) {
    DO_MFMA24(aA, bA);
    if (ks + 2 < 16) LOAD_FRAGS2(aA, bA, ks + 2);
    DO_MFMA24(aB, bB);
    if (ks + 3 < 16) LOAD_FRAGS2(aB, bB, ks + 3);
  }
#undef LOAD_FRAGS2
#undef DO_MFMA24

  float bn[4];
#pragma unroll
  for (int nt = 0; nt < 4; ++nt) bn[nt] = bias[N0 + nt * 16 + l15];
#pragma unroll
  for (int mt = 0; mt < 2; ++mt)
#pragma unroll
    for (int nt = 0; nt < 4; ++nt)
#pragma unroll
      for (int r = 0; r < 4; ++r) {
        const int m = M0 + mt * 16 + 4 * g + r;
        const int n = N0 + nt * 16 + l15;
        out[(size_t)m * 512 + n] = acc[mt][nt][r] + bn[nt];
      }
}

// MFMA flash attention. grid (64 q-tiles, 8 batches), 8 waves = 8 heads.
// One 16-row q-tile per block; tb batch-prefetched; setprio around MFMA.
__global__ __launch_bounds__(512)
void attn_mfma(const ushort* __restrict__ qb, const ushort* __restrict__ kb,
               const ushort* __restrict__ vT, const int* __restrict__ tbm,
               const float* __restrict__ temb, const int* __restrict__ lens,
               ushort* __restrict__ ab) {
  __shared__ char pbuf[8][2048];
  const int tid = threadIdx.x;
  const int w = tid >> 6;
  const int lane = tid & 63;
  const int l15 = lane & 15, g = lane >> 4;
  const int t = blockIdx.x;   // q-tile
  const int b = blockIdx.y;   // batch
  const int h = w;
  const int len = lens[b];
  const int qbase = t * 16;

  const float te_src = temb[(lane & 7) * N_HEADS + h] * 1.44269504f;

  bf16x8 qf[2];
  {
    const ushort* qrow = qb + (size_t)(b * L_SEQ + qbase + l15) * HID_DIM + h * HEAD_DIM + 8 * g;
    qf[0] = *(const bf16x8*)(qrow);
    qf[1] = *(const bf16x8*)(qrow + 32);
  }

  f32x4 O[4];
#pragma unroll
  for (int ct = 0; ct < 4; ++ct) O[ct] = (f32x4){0.f, 0.f, 0.f, 0.f};
  float ssum[4] = {0.f, 0.f, 0.f, 0.f};

  const int ke = (qbase + 16 < len) ? (qbase + 16) : len;
  const int nch = (qbase < len) ? ((ke + 63) >> 6) : 0;

  for (int c = 0; c < nch; ++c) {
    const int kc = c * 64;
    // --- batch-issue all global loads for this chunk ---
    int tb16[4][4];
    const int* tbq = tbm + (size_t)(b * L_SEQ + qbase) * L_SEQ + kc;
#pragma unroll
    for (int kt = 0; kt < 4; ++kt)
#pragma unroll
      for (int r = 0; r < 4; ++r)
        tb16[kt][r] = tbq[(4 * g + r) * L_SEQ + 16 * kt + l15];

    bf16x8 kf[4][2];
#pragma unroll
    for (int kt = 0; kt < 4; ++kt) {
      const ushort* krow = kb + (size_t)(b * L_SEQ + kc + 16 * kt + l15) * HID_DIM + h * HEAD_DIM + 8 * g;
      kf[kt][0] = *(const bf16x8*)(krow);
      kf[kt][1] = *(const bf16x8*)(krow + 32);
    }
    bf16x8 vf[2][4];
#pragma unroll
    for (int kblk = 0; kblk < 2; ++kblk)
#pragma unroll
      for (int ct = 0; ct < 4; ++ct) {
        const ushort* vrow = vT + (size_t)((b * 8 + h) * 64 + 16 * ct + l15) * L_SEQ + kc + 32 * kblk + 8 * g;
        vf[kblk][ct] = *(const bf16x8*)(vrow);
      }

    // --- QK^T: all 8 MFMAs batched ---
    f32x4 s[4];
    __builtin_amdgcn_s_setprio(1);
#pragma unroll
    for (int kt = 0; kt < 4; ++kt) {
      s[kt] = (f32x4){0.f, 0.f, 0.f, 0.f};
      s[kt] = __builtin_amdgcn_mfma_f32_16x16x32_bf16(qf[0], kf[kt][0], s[kt], 0, 0, 0);
      s[kt] = __builtin_amdgcn_mfma_f32_16x16x32_bf16(qf[1], kf[kt][1], s[kt], 0, 0, 0);
    }
    __builtin_amdgcn_s_setprio(0);

    // --- softmax (registers only; tb already resident) ---
#pragma unroll
    for (int kt = 0; kt < 4; ++kt) {
      const int kg = kc + 16 * kt + l15;
#pragma unroll
      for (int r = 0; r < 4; ++r) {
        const int lr = 4 * g + r;
        const int qg = qbase + lr;
        const float te2 = __int_as_float(
            __builtin_amdgcn_ds_bpermute(tb16[kt][r] << 2, __float_as_int(te_src)));
        float p = exp2f(fmaf(s[kt][r], 0.18033688f, te2));
        p = (kg <= qg && qg < len) ? p : 0.0f;
        const ushort pbits = f2bf(p);
        ssum[r] += __bfloat162float(*(const __hip_bfloat16*)&pbits);
        const int off = ((lr * 128 + (16 * kt + l15) * 2) ^ ((lr & 7) << 4));
        *(ushort*)&pbuf[w][off] = pbits;
      }
    }

    // --- PV ---
#pragma unroll
    for (int kblk = 0; kblk < 2; ++kblk) {
      const int off = ((l15 * 128 + kblk * 64 + 16 * g) ^ ((l15 & 7) << 4));
      const bf16x8 pf = *(const bf16x8*)(&pbuf[w][off]);
      __builtin_amdgcn_s_setprio(1);
#pragma unroll
      for (int ct = 0; ct < 4; ++ct)
        O[ct] = __builtin_amdgcn_mfma_f32_16x16x32_bf16(pf, vf[kblk][ct], O[ct], 0, 0, 0);
      __builtin_amdgcn_s_setprio(0);
    }
  }

#pragma unroll
  for (int m = 1; m <= 8; m <<= 1) {
#pragma unroll
    for (int r = 0; r < 4; ++r) ssum[r] += __shfl_xor(ssum[r], m, 64);
  }
  float inv[4];
#pragma unroll
  for (int r = 0; r < 4; ++r) {
    const int qg = qbase + 4 * g + r;
    inv[r] = (qg < len) ? 1.0f / ssum[r] : 0.0f;
  }
#pragma unroll
  for (int ct = 0; ct < 4; ++ct)
#pragma unroll
    for (int r = 0; r < 4; ++r) {
      const int qg = qbase + 4 * g + r;
      ab[(size_t)(b * L_SEQ + qg) * HID_DIM + h * HEAD_DIM + 16 * ct + l15] =
          f2bf(O[ct][r] * inv[r]);
    }
}

extern "C" void kernel_launch(void* const* d_in, const int* in_sizes, int n_in,
                              void* d_out, int out_size, void* d_ws, size_t ws_size,
                              hipStream_t stream) {
  const float* x    = (const float*)d_in[0];
  const int*   tbm  = (const int*)d_in[1];
  // d_in[2] = causal_mask: deterministic triu(k=1) -> handled analytically
  const uint8_t* pm = (const uint8_t*)d_in[3];
  const float* Wq = (const float*)d_in[4];
  const float* bq = (const float*)d_in[5];
  const float* Wk = (const float*)d_in[6];
  const float* bk = (const float*)d_in[7];
  const float* Wv = (const float*)d_in[8];
  const float* bv = (const float*)d_in[9];
  const float* Wo = (const float*)d_in[10];
  const float* bo = (const float*)d_in[11];
  const float* temb = (const float*)d_in[12];
  float* out = (float*)d_out;

  const size_t NTOK = (size_t)BATCH * L_SEQ * HID_DIM;  // 4,194,304
  const size_t NW = 262144;
  ushort* ab  = (ushort*)d_ws;        // bf16 attention output [8192][512]
  ushort* xb  = ab + NTOK;            // bf16 x
  ushort* wqb = xb + NTOK;
  ushort* wkb = wqb + NW;
  ushort* wvb = wkb + NW;
  ushort* wob = wvb + NW;
  ushort* qb  = wob + NW;             // bf16 Q [tok][512]
  ushort* kb  = qb + NTOK;            // bf16 K [tok][512]
  ushort* vT  = kb + NTOK;            // bf16 V^T [b*8+h][64][1024]
  int* lens   = (int*)(vT + NTOK);

  prep_convert<<<2560, 256, 0, stream>>>(x, Wq, Wk, Wv, Wo, xb);
  lens_kernel<<<8, 256, 0, stream>>>(pm, lens);
  qkv_gemm<<<dim3(128, 8, 3), 64, 0, stream>>>(xb, wqb, wkb, wvb, bq, bk, bv, qb, kb, vT);
  attn_mfma<<<dim3(64, 8), 512, 0, stream>>>(qb, kb, vT, tbm, temb, lens, ab);
  out_gemm<<<dim3(256, 8), 64, 0, stream>>>(ab, wob, bo, out);
}

// Round 7
// 161.329 us; speedup vs baseline: 1.2718x; 1.2718x over previous
//
#include <hip/hip_runtime.h>
#include <hip/hip_bf16.h>
#include <cstdint>

#define L_SEQ 1024
#define HID_DIM 512
#define N_HEADS 8
#define HEAD_DIM 64
#define BATCH 8

typedef __attribute__((ext_vector_type(8))) short bf16x8;
typedef __attribute__((ext_vector_type(4))) float f32x4;

__device__ __forceinline__ ushort f2bf(float v) {
  __hip_bfloat16 hb = __float2bfloat16(v);
  return *(ushort*)&hb;
}

// Convert f32 -> bf16: x (4,194,304) then Wq,Wk,Wv,Wo (262,144 each).
__global__ __launch_bounds__(256)
void prep_convert(const float* __restrict__ x, const float* __restrict__ Wq,
                  const float* __restrict__ Wk, const float* __restrict__ Wv,
                  const float* __restrict__ Wo, ushort* __restrict__ dst) {
  const size_t gid = (size_t)blockIdx.x * 256 + threadIdx.x;
  const size_t e = gid * 8;
  const float* src;
  size_t loc;
  if (e < 4194304) {
    src = x; loc = e;
  } else {
    const size_t r = e - 4194304;
    const int wsel = (int)(r >> 18);
    loc = r & 262143;
    src = (wsel == 0) ? Wq : (wsel == 1) ? Wk : (wsel == 2) ? Wv : Wo;
  }
  float4 v0 = *(const float4*)(src + loc);
  float4 v1 = *(const float4*)(src + loc + 4);
  ushort u[8];
  u[0] = f2bf(v0.x); u[1] = f2bf(v0.y); u[2] = f2bf(v0.z); u[3] = f2bf(v0.w);
  u[4] = f2bf(v1.x); u[5] = f2bf(v1.y); u[6] = f2bf(v1.z); u[7] = f2bf(v1.w);
  *(uint4*)(dst + e) = *(uint4*)u;
}

// lens[b] = number of un-padded rows in batch b (layout-detecting; see round 3)
__global__ __launch_bounds__(256)
void lens_kernel(const uint8_t* __restrict__ pm, int* __restrict__ lens) {
  __shared__ int flag;
  __shared__ int part[256];
  const int b = blockIdx.x, tid = threadIdx.x;
  if (tid == 0) flag = 0;
  __syncthreads();
  const unsigned* pw = (const unsigned*)pm;
  unsigned any = 0;
  for (int i = tid; i < 2048; i += 256) any |= (pw[i] > 1u);
  if (any) flag = 1;
  __syncthreads();
  int c = 0;
  if (flag) {
    unsigned v = pw[b * 256 + tid];
    c = (int)((v & 0xFFu) == 0) + (int)(((v >> 8) & 0xFFu) == 0) +
        (int)(((v >> 16) & 0xFFu) == 0) + (int)(((v >> 24) & 0xFFu) == 0);
  } else {
    const int* pi = (const int*)pm;
    c = (int)(pi[b * 1024 + tid * 4 + 0] == 0) + (int)(pi[b * 1024 + tid * 4 + 1] == 0) +
        (int)(pi[b * 1024 + tid * 4 + 2] == 0) + (int)(pi[b * 1024 + tid * 4 + 3] == 0);
  }
  part[tid] = c;
  __syncthreads();
  for (int s = 128; s > 0; s >>= 1) {
    if (tid < s) part[tid] += part[tid + s];
    __syncthreads();
  }
  if (tid == 0) lens[b] = part[0];
}

#define LOAD_FRAGS4(av, bv, ks)                                             \
  {                                                                         \
    _Pragma("unroll") for (int t = 0; t < 4; ++t) {                         \
      av[t] = *(const bf16x8*)(Abase + (size_t)t * 16 * 512 + (ks) * 32);   \
      bv[t] = *(const bf16x8*)(Bbase + (size_t)t * 16 * 512 + (ks) * 32);   \
    }                                                                       \
  }
#define DO_MFMA44(av, bv)                                                   \
  {                                                                         \
    _Pragma("unroll") for (int i = 0; i < 4; ++i)                           \
        _Pragma("unroll") for (int j = 0; j < 4; ++j) acc[i][j] =           \
            __builtin_amdgcn_mfma_f32_16x16x32_bf16(av[i], bv[j],           \
                                                    acc[i][j], 0, 0, 0);    \
  }

// Fused QKV GEMM, 64x64 tile per 1-wave block. grid (128, 8, 3).
__global__ __launch_bounds__(64)
void qkv_gemm(const ushort* __restrict__ xb, const ushort* __restrict__ wqb,
              const ushort* __restrict__ wkb, const ushort* __restrict__ wvb,
              const float* __restrict__ bq, const float* __restrict__ bk,
              const float* __restrict__ bv, ushort* __restrict__ qb,
              ushort* __restrict__ kb, ushort* __restrict__ vT) {
  const int z = blockIdx.z;
  const int lane = threadIdx.x;
  const int l15 = lane & 15, g = lane >> 4;
  const ushort* A = (z == 2) ? wvb : xb;
  const ushort* B = (z == 0) ? wqb : (z == 1) ? wkb : xb;
  const float* bias = (z == 0) ? bq : (z == 1) ? bk : bv;
  const int M0 = ((z == 2) ? blockIdx.y : blockIdx.x) * 64;
  const int N0 = ((z == 2) ? blockIdx.x : blockIdx.y) * 64;

  const ushort* Abase = A + (size_t)(M0 + l15) * 512 + 8 * g;
  const ushort* Bbase = B + (size_t)(N0 + l15) * 512 + 8 * g;

  f32x4 acc[4][4];
#pragma unroll
  for (int i = 0; i < 4; ++i)
#pragma unroll
    for (int j = 0; j < 4; ++j) acc[i][j] = (f32x4){0.f, 0.f, 0.f, 0.f};

  bf16x8 aA[4], bA[4], aB[4], bB[4];
  LOAD_FRAGS4(aA, bA, 0);
  LOAD_FRAGS4(aB, bB, 1);
#pragma unroll
  for (int ks = 0; ks < 16; ks += 2) {
    DO_MFMA44(aA, bA);
    if (ks + 2 < 16) LOAD_FRAGS4(aA, bA, ks + 2);
    DO_MFMA44(aB, bB);
    if (ks + 3 < 16) LOAD_FRAGS4(aB, bB, ks + 3);
  }

  if (z < 2) {
    ushort* out = (z == 0) ? qb : kb;
    float bn[4];
#pragma unroll
    for (int nt = 0; nt < 4; ++nt) bn[nt] = bias[N0 + nt * 16 + l15];
#pragma unroll
    for (int mt = 0; mt < 4; ++mt)
#pragma unroll
      for (int nt = 0; nt < 4; ++nt)
#pragma unroll
        for (int r = 0; r < 4; ++r) {
          const int m = M0 + mt * 16 + 4 * g + r;
          const int n = N0 + nt * 16 + l15;
          out[(size_t)m * 512 + n] = f2bf(acc[mt][nt][r] + bn[nt]);
        }
  } else {
#pragma unroll
    for (int mt = 0; mt < 4; ++mt)
#pragma unroll
      for (int r = 0; r < 4; ++r) {
        const int m = M0 + mt * 16 + 4 * g + r;  // hid index of V
        const float bm = bias[m];
#pragma unroll
        for (int nt = 0; nt < 4; ++nt) {
          const int tok = N0 + nt * 16 + l15;
          const size_t off = ((size_t)((tok >> 10) * 512 + m)) * 1024 + (tok & 1023);
          vT[off] = f2bf(acc[mt][nt][r] + bm);
        }
      }
  }
}

// Final projection: out = ab*Wo^T + bo, f32 out. 32x64 tile. grid (256, 8).
__global__ __launch_bounds__(64)
void out_gemm(const ushort* __restrict__ A, const ushort* __restrict__ B,
              const float* __restrict__ bias, float* __restrict__ out) {
  const int lane = threadIdx.x;
  const int l15 = lane & 15, g = lane >> 4;
  const int M0 = blockIdx.x * 32, N0 = blockIdx.y * 64;
  const ushort* Abase = A + (size_t)(M0 + l15) * 512 + 8 * g;
  const ushort* Bbase = B + (size_t)(N0 + l15) * 512 + 8 * g;

  f32x4 acc[2][4];
#pragma unroll
  for (int i = 0; i < 2; ++i)
#pragma unroll
    for (int j = 0; j < 4; ++j) acc[i][j] = (f32x4){0.f, 0.f, 0.f, 0.f};

  bf16x8 aA[2], bA[4], aB[2], bB[4];
#define LOAD_FRAGS2(av, bv, ks)                                             \
  {                                                                         \
    _Pragma("unroll") for (int t = 0; t < 2; ++t)                           \
      av[t] = *(const bf16x8*)(Abase + (size_t)t * 16 * 512 + (ks) * 32);   \
    _Pragma("unroll") for (int t = 0; t < 4; ++t)                           \
      bv[t] = *(const bf16x8*)(Bbase + (size_t)t * 16 * 512 + (ks) * 32);   \
  }
#define DO_MFMA24(av, bv)                                                   \
  {                                                                         \
    _Pragma("unroll") for (int i = 0; i < 2; ++i)                           \
        _Pragma("unroll") for (int j = 0; j < 4; ++j) acc[i][j] =           \
            __builtin_amdgcn_mfma_f32_16x16x32_bf16(av[i], bv[j],           \
                                                    acc[i][j], 0, 0, 0);    \
  }
  LOAD_FRAGS2(aA, bA, 0);
  LOAD_FRAGS2(aB, bB, 1);
#pragma unroll
  for (int ks = 0; ks < 16; ks += 2) {
    DO_MFMA24(aA, bA);
    if (ks + 2 < 16) LOAD_FRAGS2(aA, bA, ks + 2);
    DO_MFMA24(aB, bB);
    if (ks + 3 < 16) LOAD_FRAGS2(aB, bB, ks + 3);
  }
#undef LOAD_FRAGS2
#undef DO_MFMA24

  float bn[4];
#pragma unroll
  for (int nt = 0; nt < 4; ++nt) bn[nt] = bias[N0 + nt * 16 + l15];
#pragma unroll
  for (int mt = 0; mt < 2; ++mt)
#pragma unroll
    for (int nt = 0; nt < 4; ++nt)
#pragma unroll
      for (int r = 0; r < 4; ++r) {
        const int m = M0 + mt * 16 + 4 * g + r;
        const int n = N0 + nt * 16 + l15;
        out[(size_t)m * 512 + n] = acc[mt][nt][r] + bn[nt];
      }
}

// MFMA flash attention. grid (x=8 batches, y=64 q-tiles) -> linear id % 8 = b
// keeps each batch's K/V/tbm on ONE XCD's L2 (round-5 locality), while 512
// blocks give 2 blocks/CU (4 waves/SIMD). LPT: t = 63 - y (big tiles first).
// tb indices double-buffered across chunks (named bufs, unroll-2).
__global__ __launch_bounds__(512)
void attn_mfma(const ushort* __restrict__ qb, const ushort* __restrict__ kb,
               const ushort* __restrict__ vT, const int* __restrict__ tbm,
               const float* __restrict__ temb, const int* __restrict__ lens,
               ushort* __restrict__ ab) {
  __shared__ char pbuf[8][2048];
  const int tid = threadIdx.x;
  const int w = tid >> 6;
  const int lane = tid & 63;
  const int l15 = lane & 15, g = lane >> 4;
  const int b = blockIdx.x;          // batch -> XCD (locality)
  const int t = 63 - blockIdx.y;     // LPT: longest tiles first
  const int h = w;
  const int len = lens[b];
  const int qbase = t * 16;

  const float te_src = temb[(lane & 7) * N_HEADS + h] * 1.44269504f;

  bf16x8 qf[2];
  {
    const ushort* qrow = qb + (size_t)(b * L_SEQ + qbase + l15) * HID_DIM + h * HEAD_DIM + 8 * g;
    qf[0] = *(const bf16x8*)(qrow);
    qf[1] = *(const bf16x8*)(qrow + 32);
  }

  f32x4 O[4];
#pragma unroll
  for (int ct = 0; ct < 4; ++ct) O[ct] = (f32x4){0.f, 0.f, 0.f, 0.f};
  float ssum[4] = {0.f, 0.f, 0.f, 0.f};

  const int ke = (qbase + 16 < len) ? (qbase + 16) : len;
  const int nch = (qbase < len) ? ((ke + 63) >> 6) : 0;
  const int* tbq = tbm + (size_t)(b * L_SEQ + qbase) * L_SEQ;

#define LOAD_TB(dst, cc)                                                    \
  {                                                                         \
    const int* tb_p = tbq + (cc) * 64;                                      \
    _Pragma("unroll") for (int kt = 0; kt < 4; ++kt)                        \
        _Pragma("unroll") for (int r = 0; r < 4; ++r)                       \
            dst[kt][r] = tb_p[(4 * g + r) * L_SEQ + 16 * kt + l15];         \
  }

#define COMPUTE_CHUNK(tbv, c)                                               \
  {                                                                         \
    const int kc = (c) * 64;                                                \
    bf16x8 kf[4][2];                                                        \
    _Pragma("unroll") for (int kt = 0; kt < 4; ++kt) {                      \
      const ushort* krow = kb + (size_t)(b * L_SEQ + kc + 16 * kt + l15) * HID_DIM + h * HEAD_DIM + 8 * g; \
      kf[kt][0] = *(const bf16x8*)(krow);                                   \
      kf[kt][1] = *(const bf16x8*)(krow + 32);                              \
    }                                                                       \
    bf16x8 vf[2][4];                                                        \
    _Pragma("unroll") for (int kblk = 0; kblk < 2; ++kblk)                  \
        _Pragma("unroll") for (int ct = 0; ct < 4; ++ct) {                  \
      const ushort* vrow = vT + (size_t)((b * 8 + h) * 64 + 16 * ct + l15) * L_SEQ + kc + 32 * kblk + 8 * g; \
      vf[kblk][ct] = *(const bf16x8*)(vrow);                                \
    }                                                                       \
    f32x4 s[4];                                                             \
    __builtin_amdgcn_s_setprio(1);                                          \
    _Pragma("unroll") for (int kt = 0; kt < 4; ++kt) {                      \
      s[kt] = (f32x4){0.f, 0.f, 0.f, 0.f};                                  \
      s[kt] = __builtin_amdgcn_mfma_f32_16x16x32_bf16(qf[0], kf[kt][0], s[kt], 0, 0, 0); \
      s[kt] = __builtin_amdgcn_mfma_f32_16x16x32_bf16(qf[1], kf[kt][1], s[kt], 0, 0, 0); \
    }                                                                       \
    __builtin_amdgcn_s_setprio(0);                                          \
    _Pragma("unroll") for (int kt = 0; kt < 4; ++kt) {                      \
      const int kg = kc + 16 * kt + l15;                                    \
      _Pragma("unroll") for (int r = 0; r < 4; ++r) {                       \
        const int lr = 4 * g + r;                                           \
        const int qg = qbase + lr;                                          \
        const float te2 = __int_as_float(                                   \
            __builtin_amdgcn_ds_bpermute(tbv[kt][r] << 2, __float_as_int(te_src))); \
        float p = exp2f(fmaf(s[kt][r], 0.18033688f, te2));                  \
        p = (kg <= qg && qg < len) ? p : 0.0f;                              \
        const ushort pbits = f2bf(p);                                       \
        ssum[r] += __bfloat162float(*(const __hip_bfloat16*)&pbits);        \
        const int off = ((lr * 128 + (16 * kt + l15) * 2) ^ ((lr & 7) << 4)); \
        *(ushort*)&pbuf[w][off] = pbits;                                    \
      }                                                                     \
    }                                                                       \
    _Pragma("unroll") for (int kblk = 0; kblk < 2; ++kblk) {                \
      const int off = ((l15 * 128 + kblk * 64 + 16 * g) ^ ((l15 & 7) << 4)); \
      const bf16x8 pf = *(const bf16x8*)(&pbuf[w][off]);                    \
      __builtin_amdgcn_s_setprio(1);                                        \
      _Pragma("unroll") for (int ct = 0; ct < 4; ++ct)                      \
        O[ct] = __builtin_amdgcn_mfma_f32_16x16x32_bf16(pf, vf[kblk][ct], O[ct], 0, 0, 0); \
      __builtin_amdgcn_s_setprio(0);                                        \
    }                                                                       \
  }

  int tbA[4][4], tbB[4][4];
  if (nch > 0) LOAD_TB(tbA, 0);
  int c = 0;
  while (c < nch) {
    if (c + 1 < nch) LOAD_TB(tbB, c + 1);
    COMPUTE_CHUNK(tbA, c);
    ++c;
    if (c >= nch) break;
    if (c + 1 < nch) LOAD_TB(tbA, c + 1);
    COMPUTE_CHUNK(tbB, c);
    ++c;
  }
#undef LOAD_TB
#undef COMPUTE_CHUNK

#pragma unroll
  for (int m = 1; m <= 8; m <<= 1) {
#pragma unroll
    for (int r = 0; r < 4; ++r) ssum[r] += __shfl_xor(ssum[r], m, 64);
  }
  float inv[4];
#pragma unroll
  for (int r = 0; r < 4; ++r) {
    const int qg = qbase + 4 * g + r;
    inv[r] = (qg < len) ? 1.0f / ssum[r] : 0.0f;
  }
#pragma unroll
  for (int ct = 0; ct < 4; ++ct)
#pragma unroll
    for (int r = 0; r < 4; ++r) {
      const int qg = qbase + 4 * g + r;
      ab[(size_t)(b * L_SEQ + qg) * HID_DIM + h * HEAD_DIM + 16 * ct + l15] =
          f2bf(O[ct][r] * inv[r]);
    }
}

extern "C" void kernel_launch(void* const* d_in, const int* in_sizes, int n_in,
                              void* d_out, int out_size, void* d_ws, size_t ws_size,
                              hipStream_t stream) {
  const float* x    = (const float*)d_in[0];
  const int*   tbm  = (const int*)d_in[1];
  // d_in[2] = causal_mask: deterministic triu(k=1) -> handled analytically
  const uint8_t* pm = (const uint8_t*)d_in[3];
  const float* Wq = (const float*)d_in[4];
  const float* bq = (const float*)d_in[5];
  const float* Wk = (const float*)d_in[6];
  const float* bk = (const float*)d_in[7];
  const float* Wv = (const float*)d_in[8];
  const float* bv = (const float*)d_in[9];
  const float* Wo = (const float*)d_in[10];
  const float* bo = (const float*)d_in[11];
  const float* temb = (const float*)d_in[12];
  float* out = (float*)d_out;

  const size_t NTOK = (size_t)BATCH * L_SEQ * HID_DIM;  // 4,194,304
  const size_t NW = 262144;
  ushort* ab  = (ushort*)d_ws;        // bf16 attention output [8192][512]
  ushort* xb  = ab + NTOK;            // bf16 x
  ushort* wqb = xb + NTOK;
  ushort* wkb = wqb + NW;
  ushort* wvb = wkb + NW;
  ushort* wob = wvb + NW;
  ushort* qb  = wob + NW;             // bf16 Q [tok][512]
  ushort* kb  = qb + NTOK;            // bf16 K [tok][512]
  ushort* vT  = kb + NTOK;            // bf16 V^T [b*8+h][64][1024]
  int* lens   = (int*)(vT + NTOK);

  prep_convert<<<2560, 256, 0, stream>>>(x, Wq, Wk, Wv, Wo, xb);
  lens_kernel<<<8, 256, 0, stream>>>(pm, lens);
  qkv_gemm<<<dim3(128, 8, 3), 64, 0, stream>>>(xb, wqb, wkb, wvb, bq, bk, bv, qb, kb, vT);
  attn_mfma<<<dim3(8, 64), 512, 0, stream>>>(qb, kb, vT, tbm, temb, lens, ab);
  out_gemm<<<dim3(256, 8), 64, 0, stream>>>(ab, wob, bo, out);
}